// Round 13
// baseline (183.627 us; speedup 1.0000x reference)
//
#include <hip/hip_runtime.h>
#include <hip/hip_bf16.h>
#include <math.h>

#define NB 4
#define NN 128
#define NF 128
#define NS 5
#define NT 32
#define NL 2

typedef __hip_bfloat16 bf16;
typedef short bf16x8 __attribute__((ext_vector_type(8)));
typedef float f32x4 __attribute__((ext_vector_type(4)));

__device__ __forceinline__ float b2f(const bf16 x) { return __bfloat162float(x); }
__device__ __forceinline__ float fast_rcp(float x) { return __builtin_amdgcn_rcpf(x); }
__device__ __forceinline__ float fast_rsq(float x) { return __builtin_amdgcn_rsqf(x); }
__device__ __forceinline__ float silu_fast(float x) { return x * fast_rcp(1.0f + __expf(-x)); }
__device__ __forceinline__ float ldf(const void* p, int i, int fl) {
  return fl ? b2f(((const bf16*)p)[i]) : ((const float*)p)[i];
}
// float -> bf16 bits (RNE)
__device__ __forceinline__ short f2bf(float x) {
  unsigned u = __float_as_uint(x);
  unsigned r = (u + 0x7fffu + ((u >> 16) & 1u)) >> 16;
  return (short)r;
}

#define PI_F 3.14159265358979323846f
#define SQRT3_F 1.7320508075688772f

// converted-weights region offsets (floats) within d_ws after the flag slot
#define POS_OFF 0
#define GF_OFF  1536
#define WE_OFF  1664
#define BE_OFF  6400
#define WR1_OFF 6528
#define BR1_OFF 6656
#define WR2_OFF 6784
#define WN_OFF  72320
#define C1_OFF  105088
#define C2_OFF  106112
#define C3_OFF  107136
#define M0_OFF  108160
#define M1_OFF  140928
#define G1_OFF  173696
#define G2_OFF  177792
#define WV_OFF  181888
#define CVT_TOTAL 182144

// ---------------------------------------------------------------------------
// prep_convert: detect dtype, convert cvt region, prep node rows:
// env row, z layer-0, vec=0, posA. (Ag no longer exists.)
// ---------------------------------------------------------------------------
__global__ void prep_convert_kernel(
    const void* __restrict__ pos_raw, const int* __restrict__ nfeat,
    const void* __restrict__ gf,  const void* __restrict__ we,
    const void* __restrict__ be,  const void* __restrict__ wr1,
    const void* __restrict__ br1, const void* __restrict__ wr2,
    const void* __restrict__ wn,  const void* __restrict__ c1,
    const void* __restrict__ c2,  const void* __restrict__ c3,
    const void* __restrict__ m0,  const void* __restrict__ m1,
    const void* __restrict__ g1,  const void* __restrict__ g2,
    const void* __restrict__ wv,
    int* __restrict__ flag, float* __restrict__ cvt,
    float* __restrict__ posA, float* __restrict__ z,
    float* __restrict__ vec, float* __restrict__ env)
{
  __shared__ float posB[NN*3];
  __shared__ float scs[NF];
  __shared__ int sbad;
  const int tid = threadIdx.x;
  const int bn  = blockIdx.x;        // node row, 0..511
  const int b   = bn >> 7;
  const int n   = bn & 127;

  if (tid == 0) sbad = 0;
  __syncthreads();
  {
    const bf16* p = (const bf16*)pos_raw;
    int bad = 0;
    for (int i = tid; i < NB*NN*3; i += 256) {
      float v = b2f(p[i]);
      if (!(fabsf(v) <= 1024.0f)) bad = 1;   // NaN also fails
    }
    if (bad) sbad = 1;
  }
  __syncthreads();
  const int fl = sbad ? 0 : 1;               // 1 = bf16 inputs
  if (bn == 0 && tid == 0) *flag = fl;

  for (int i = bn*256 + tid; i < CVT_TOTAL; i += 512*256) {
    const void* src; int j;
    if      (i < GF_OFF)  { src = pos_raw; j = i - POS_OFF; }
    else if (i < WE_OFF)  { src = gf;  j = i - GF_OFF; }
    else if (i < BE_OFF)  { src = we;  j = i - WE_OFF; }
    else if (i < WR1_OFF) { src = be;  j = i - BE_OFF; }
    else if (i < BR1_OFF) { src = wr1; j = i - WR1_OFF; }
    else if (i < WR2_OFF) { src = br1; j = i - BR1_OFF; }
    else if (i < WN_OFF)  { src = wr2; j = i - WR2_OFF; }
    else if (i < C1_OFF)  { src = wn;  j = i - WN_OFF; }
    else if (i < C2_OFF)  { src = c1;  j = i - C1_OFF; }
    else if (i < C3_OFF)  { src = c2;  j = i - C2_OFF; }
    else if (i < M0_OFF)  { src = c3;  j = i - C3_OFF; }
    else if (i < M1_OFF)  { src = m0;  j = i - M0_OFF; }
    else if (i < G1_OFF)  { src = m1;  j = i - M1_OFF; }
    else if (i < G2_OFF)  { src = g1;  j = i - G1_OFF; }
    else if (i < WV_OFF)  { src = g2;  j = i - G2_OFF; }
    else                  { src = wv;  j = i - WV_OFF; }
    cvt[i] = fl ? b2f(((const bf16*)src)[j]) : ((const float*)src)[j];
  }

  for (int i = tid; i < NN*3; i += 256)
    posB[i] = ldf(pos_raw, b*NN*3 + i, fl);
  if (tid < 128) {
    int sp = nfeat[bn] - 1;
    float acc = ldf(we, sp*NF + tid, fl) + ldf(be, tid, fl);
    #pragma unroll 8
    for (int t = 0; t < NT; ++t)
      acc += ldf(gf, b*NT + t, fl) * ldf(we, (NS + t)*NF + tid, fl);
    scs[tid] = acc;
  }
  __syncthreads();

  if (tid < 128) {
    const int f = tid;
    {
      float px = posB[n*3+0], py = posB[n*3+1], pz = posB[n*3+2];
      float vx = px - posB[f*3+0];
      float vy = py - posB[f*3+1];
      float vz = pz - posB[f*3+2];
      float lng = sqrtf(vx*vx + vy*vy + vz*vz + 1e-12f);
      env[bn*NN + f] = (lng < 10.0f) ? 0.5f*(cosf(PI_F*lng*0.1f) + 1.0f) : 0.0f;
    }
    {
      float acc = 0.f;
      if (fl) {
        const bf16* W = (const bf16*)wn;
        #pragma unroll 8
        for (int k = 0; k < NF; ++k) acc += scs[k] * b2f(W[k*NF + f]);
      } else {
        const float* W = (const float*)wn;
        #pragma unroll 8
        for (int k = 0; k < NF; ++k) acc += scs[k] * W[k*NF + f];
      }
      z[bn*NF + f] = acc;
    }
    vec[((size_t)bn*3 + 0)*NF + f] = 0.f;
    vec[((size_t)bn*3 + 1)*NF + f] = 0.f;
    vec[((size_t)bn*3 + 2)*NF + f] = 0.f;
    if (f < 3) posA[bn*3 + f] = posB[n*3 + f];
  }
}

// ---------------------------------------------------------------------------
// LAYER kernel (edge + node fused, zero atomics): grid = NB*64 = 256 blocks,
// one block = (batch, 2 receivers) x all 128 senders.
// Edge phase: 16 chunks of 8 senders; MFMA M-tile = 16 edges = 2 recv x 8
// senders (C row m=q*4+reg -> recv=m>>3, sender=m&7). VGPR accum;
// per-(q,c,f) unique epilogue store into LDS Ash (two q per (recv,f) summed
// in node phase). Node phase: gate + mix GEMMs + gate MLP + pos update for
// the block's 2 rows. Cross-launch ping-pong (in/out buffers) kills races.
// ---------------------------------------------------------------------------
__global__ __launch_bounds__(256, 2)
void layer_kernel(const float* __restrict__ pos_in,
                  const float* __restrict__ z_in,
                  const float* __restrict__ vec_in,
                  const float* __restrict__ env,
                  const float* __restrict__ cvt,
                  int layer, int last,
                  float* __restrict__ pos_out,
                  float* __restrict__ z_out,
                  float* __restrict__ vec_out,
                  const int* __restrict__ flag,
                  void* __restrict__ out)
{
  __shared__ float posL[NN*3];                     // 1.5 KB
  __shared__ float envL[2][NN];                    // 1 KB
  __shared__ float w1L[64], b1L[64];
  __shared__ __align__(16) short hidA[2][16][72];  // 4.5 KB
  __shared__ __align__(16) float4 zvp[2][8][NF];   // 32 KB
  __shared__ __align__(16) float4 uenvL[2][2][8];  // [buf][recv][sender]
  __shared__ float Ash[4][4][NF];                  // 8 KB [q][c][f]
  __shared__ float scs[2][NF];
  __shared__ float h16[2][16];
  __shared__ float red[4][3];

  const int tid  = threadIdx.x;
  const int bidx = blockIdx.x;                   // b*64 + rt
  const int b    = bidx >> 6;
  const int rt   = bidx & 63;
  const int r0   = rt * 2;

  const int wvid  = tid >> 6;                    // wave 0..3
  const int lane  = tid & 63;
  const int n16   = lane & 15;                   // MFMA n / A-row
  const int q     = lane >> 4;                   // quarter
  const int halfB = wvid >> 1;                   // 0: ell0 cols, 1: ell1
  const int col   = wvid*64 + n16;               // + t*16 below

  // ---- prologue ----
  for (int i = tid; i < NN*3; i += 256)
    posL[i] = pos_in[b*NN*3 + i];
  if (tid < 128) {
    envL[0][tid] = env[(b*NN + r0 + 0)*NN + tid];
    envL[1][tid] = env[(b*NN + r0 + 1)*NN + tid];
  }
  if (tid < 64) {
    w1L[tid] = cvt[WR1_OFF + layer*64 + tid];
    b1L[tid] = cvt[BR1_OFF + layer*64 + tid];
  }
  bf16x8 bfr[4][2];
  {
    const float* W2 = cvt + WR2_OFF + layer*64*512;
    #pragma unroll
    for (int t = 0; t < 4; ++t) {
      int c512 = col + t*16;                     // 0..255
      #pragma unroll
      for (int ks = 0; ks < 2; ++ks) {
        #pragma unroll
        for (int j = 0; j < 8; ++j) {
          int k = ks*32 + q*8 + j;
          float v = W2[k*512 + c512];
          if (halfB) v *= SQRT3_F;
          bfr[t][ks][j] = f2bf(v);
        }
      }
    }
  }
  float acR[12];
  #pragma unroll
  for (int i = 0; i < 12; ++i) acR[i] = 0.f;

  __syncthreads();

  // hid staging: wave wvid stages edge rows wvid*4+i; receiver rvW fixed/wave
  const int rvW   = wvid >> 1;
  const int slocW = (wvid & 1) * 4;              // sender-local base
  const float hrx = posL[(r0 + rvW)*3 + 0];
  const float hry = posL[(r0 + rvW)*3 + 1];
  const float hrz = posL[(r0 + rvW)*3 + 2];
  const float w1v = w1L[lane], b1v = b1L[lane];

  const int fS  = tid & 127;                     // zvp staging column
  const int si0 = tid >> 7;                      // zvp staging sender base

  float4 pv[4];

  // ---- stage chunk 0 into buf 0 ----
  #pragma unroll
  for (int rep = 0; rep < 4; ++rep) {
    int gs = b*NN + si0 + 2*rep;
    pv[rep].x = z_in[gs*NF + fS];
    pv[rep].y = vec_in[((size_t)gs*3 + 0)*NF + fS];
    pv[rep].z = vec_in[((size_t)gs*3 + 1)*NF + fS];
    pv[rep].w = vec_in[((size_t)gs*3 + 2)*NF + fS];
  }
  #pragma unroll
  for (int i = 0; i < 4; ++i) {
    int s = slocW + i;                           // sender 0..7 in chunk 0
    float vx = hrx - posL[s*3 + 0];
    float vy = hry - posL[s*3 + 1];
    float vz = hrz - posL[s*3 + 2];
    float d = vx*vx + vy*vy + vz*vz + 1e-12f;
    float lng = d * fast_rsq(d);
    hidA[0][rvW*8 + slocW + i][lane] = f2bf(silu_fast(lng * w1v + b1v));
  }
  if (tid < 16) {
    int r = tid >> 3, si = tid & 7;
    int s = si;
    float vx = posL[(r0 + r)*3 + 0] - posL[s*3 + 0];
    float vy = posL[(r0 + r)*3 + 1] - posL[s*3 + 1];
    float vz = posL[(r0 + r)*3 + 2] - posL[s*3 + 2];
    float d = vx*vx + vy*vy + vz*vz + 1e-12f;
    float inv = fast_rsq(d);
    float envw = (s == r0 + r) ? 0.f : envL[r][si] * 0.0625f;
    uenvL[0][r][si] = make_float4(vx*inv, vy*inv, vz*inv, envw);
  }
  #pragma unroll
  for (int rep = 0; rep < 4; ++rep)
    zvp[0][si0 + 2*rep][fS] = pv[rep];
  __syncthreads();

  // lane's consume identity: receiver qr, 4 senders sb..sb+3 (local)
  const int qr = q >> 1;
  const int sb = (q & 1) * 4;

  // ---- pipelined chunk loop: 16 chunks of 8 senders, 1 barrier each ----
  for (int c = 0; c < 16; ++c) {
    const int cb = c & 1, nb = cb ^ 1;
    const int nc0 = (c + 1) * 8;

    if (c < 15) {
      #pragma unroll
      for (int rep = 0; rep < 4; ++rep) {
        int gs = b*NN + nc0 + si0 + 2*rep;
        pv[rep].x = z_in[gs*NF + fS];
        pv[rep].y = vec_in[((size_t)gs*3 + 0)*NF + fS];
        pv[rep].z = vec_in[((size_t)gs*3 + 1)*NF + fS];
        pv[rep].w = vec_in[((size_t)gs*3 + 2)*NF + fS];
      }
    }

    // ---- MFMA + consume (buffer cb) ----
    bf16x8 af0 = *(const bf16x8*)&hidA[cb][n16][q*8];
    bf16x8 af1 = *(const bf16x8*)&hidA[cb][n16][q*8 + 32];
    float4 ue[4];
    #pragma unroll
    for (int si = 0; si < 4; ++si) ue[si] = uenvL[cb][qr][sb + si];

    #pragma unroll
    for (int t = 0; t < 4; ++t) {
      f32x4 Cf = {0.f, 0.f, 0.f, 0.f};
      Cf = __builtin_amdgcn_mfma_f32_16x16x32_bf16(af0, bfr[t][0], Cf, 0, 0, 0);
      Cf = __builtin_amdgcn_mfma_f32_16x16x32_bf16(af1, bfr[t][1], Cf, 0, 0, 0);
      int f = (col + t*16) & 127;
      if (!halfB) {
        float a0 = 0.f;
        #pragma unroll
        for (int si = 0; si < 4; ++si) {
          float4 zv = zvp[cb][sb + si][f];
          float fv = zv.x + ue[si].x*zv.y + ue[si].y*zv.z + ue[si].z*zv.w;
          a0 += (Cf[si] * ue[si].w) * fv;
        }
        acR[t] += a0;
      } else {
        float t1 = 0.f, t2 = 0.f, t3 = 0.f;
        #pragma unroll
        for (int si = 0; si < 4; ++si) {
          float4 zv = zvp[cb][sb + si][f];
          float fv = zv.x + ue[si].x*zv.y + ue[si].y*zv.z + ue[si].z*zv.w;
          float tt = (Cf[si] * ue[si].w) * fv;   // sqrt3 folded into B
          t1 += tt * ue[si].x;
          t2 += tt * ue[si].y;
          t3 += tt * ue[si].z;
        }
        acR[t*3 + 0] += t1;
        acR[t*3 + 1] += t2;
        acR[t*3 + 2] += t3;
      }
    }

    // ---- stage next chunk into buffer nb ----
    if (c < 15) {
      #pragma unroll
      for (int i = 0; i < 4; ++i) {
        int s = nc0 + slocW + i;
        float vx = hrx - posL[s*3 + 0];
        float vy = hry - posL[s*3 + 1];
        float vz = hrz - posL[s*3 + 2];
        float d = vx*vx + vy*vy + vz*vz + 1e-12f;
        float lng = d * fast_rsq(d);
        hidA[nb][rvW*8 + slocW + i][lane] = f2bf(silu_fast(lng * w1v + b1v));
      }
      if (tid < 16) {
        int r = tid >> 3, si = tid & 7;
        int s = nc0 + si;
        float vx = posL[(r0 + r)*3 + 0] - posL[s*3 + 0];
        float vy = posL[(r0 + r)*3 + 1] - posL[s*3 + 1];
        float vz = posL[(r0 + r)*3 + 2] - posL[s*3 + 2];
        float d = vx*vx + vy*vy + vz*vz + 1e-12f;
        float inv = fast_rsq(d);
        float envw = (s == r0 + r) ? 0.f : envL[r][s] * 0.0625f;
        uenvL[nb][r][si] = make_float4(vx*inv, vy*inv, vz*inv, envw);
      }
      #pragma unroll
      for (int rep = 0; rep < 4; ++rep)
        zvp[nb][si0 + 2*rep][fS] = pv[rep];
    }
    __syncthreads();
  }

  // ---- edge epilogue: unique (q,c,f) stores into LDS ----
  if (!halfB) {
    #pragma unroll
    for (int t = 0; t < 4; ++t)
      Ash[q][0][(col + t*16) & 127] = acR[t];
  } else {
    #pragma unroll
    for (int t = 0; t < 4; ++t) {
      int f = (col + t*16) & 127;
      Ash[q][1][f] = acR[t*3 + 0];
      Ash[q][2][f] = acR[t*3 + 1];
      Ash[q][3][f] = acR[t*3 + 2];
    }
  }
  __syncthreads();

  // =================== NODE phase: 2 rows, 256 threads ===================
  const int rowh = tid >> 7;                     // 0/1
  const int f    = tid & 127;
  const int bn   = b*NN + r0 + rowh;

  // sum the two q-slots, apply correlation gate, store gated into slot q=row*2
  {
    float a0 = Ash[rowh*2][0][f] + Ash[rowh*2+1][0][f];
    float a1 = Ash[rowh*2][1][f] + Ash[rowh*2+1][1][f];
    float a2 = Ash[rowh*2][2][f] + Ash[rowh*2+1][2][f];
    float a3 = Ash[rowh*2][3][f] + Ash[rowh*2+1][3][f];
    float n0 = a0*a0;
    float C1 = cvt[C1_OFF + (layer*4 + 0)*NF + f];
    float C2 = cvt[C2_OFF + (layer*4 + 0)*NF + f];
    float C3 = cvt[C3_OFF + (layer*4 + 0)*NF + f];
    float g0 = 1.0f + C1*n0 + C2*n0*n0 + C3*n0*n0*n0;
    float n1 = a1*a1 + a2*a2 + a3*a3;
    float D1 = cvt[C1_OFF + (layer*4 + 1)*NF + f];
    float D2 = cvt[C2_OFF + (layer*4 + 1)*NF + f];
    float D3 = cvt[C3_OFF + (layer*4 + 1)*NF + f];
    float g1 = 1.0f + D1*n1 + D2*n1*n1 + D3*n1*n1*n1;
    __syncthreads();                             // all reads done before overwrite
    Ash[rowh*2][0][f] = a0 * g0;
    Ash[rowh*2][1][f] = a1 * g1;
    Ash[rowh*2][2][f] = a2 * g1;
    Ash[rowh*2][3][f] = a3 * g1;
  }
  __syncthreads();

  const float* M0 = cvt + M0_OFF + layer*NF*NF;
  const float* M1 = cvt + M1_OFF + layer*NF*NF;
  float sn = 0.f, v0 = 0.f, v1 = 0.f, v2 = 0.f;
  #pragma unroll 4
  for (int k = 0; k < NF; ++k) {
    float m0 = M0[k*NF + f];
    float m1 = M1[k*NF + f];
    sn += Ash[rowh*2][0][k] * m0;
    v0 += Ash[rowh*2][1][k] * m1;
    v1 += Ash[rowh*2][2][k] * m1;
    v2 += Ash[rowh*2][3][k] * m1;
  }
  scs[rowh][f] = sn;
  __syncthreads();

  if (!last) {
    const float* W = cvt + WN_OFF + (layer+1)*NF*NF;
    float acc = 0.f;
    #pragma unroll 8
    for (int k = 0; k < NF; ++k)
      acc += scs[rowh][k] * W[k*NF + f];
    z_out[bn*NF + f] = acc;
  }
  if (f < 16) {
    const float* G1 = cvt + G1_OFF + layer*NF*16;
    float acc = 0.f;
    #pragma unroll 8
    for (int k = 0; k < NF; ++k)
      acc += scs[rowh][k] * G1[k*16 + f];
    h16[rowh][f] = silu_fast(acc);
  }
  __syncthreads();

  {
    const float* G2 = cvt + G2_OFF + layer*16*NF;
    float gate = 0.f;
    #pragma unroll
    for (int j = 0; j < 16; ++j)
      gate += h16[rowh][j] * G2[j*NF + f];
    float gv = gate * cvt[WV_OFF + layer*NF + f];

    if (!last) {
      vec_out[((size_t)bn*3 + 0)*NF + f] = v0;
      vec_out[((size_t)bn*3 + 1)*NF + f] = v1;
      vec_out[((size_t)bn*3 + 2)*NF + f] = v2;
    }

    float p0 = v0*gv, p1 = v1*gv, p2 = v2*gv;
    #pragma unroll
    for (int off = 32; off > 0; off >>= 1) {
      p0 += __shfl_down(p0, off, 64);
      p1 += __shfl_down(p1, off, 64);
      p2 += __shfl_down(p2, off, 64);
    }
    if (lane == 0) { red[wvid][0] = p0; red[wvid][1] = p1; red[wvid][2] = p2; }
  }
  __syncthreads();

  if (f == 0) {                                  // tid 0 (row 0), tid 128 (row 1)
    float m0 = red[rowh*2][0] + red[rowh*2+1][0];
    float m1 = red[rowh*2][1] + red[rowh*2+1][1];
    float m2 = red[rowh*2][2] + red[rowh*2+1][2];
    float px = posL[(r0 + rowh)*3 + 0] + m0;
    float py = posL[(r0 + rowh)*3 + 1] + m1;
    float pz = posL[(r0 + rowh)*3 + 2] + m2;
    if (!last) {
      pos_out[bn*3+0] = px;
      pos_out[bn*3+1] = py;
      pos_out[bn*3+2] = pz;
    } else {
      float ox = px - cvt[POS_OFF + bn*3+0];
      float oy = py - cvt[POS_OFF + bn*3+1];
      float oz = pz - cvt[POS_OFF + bn*3+2];
      if (*flag) {
        bf16* o = (bf16*)out;
        o[bn*3+0] = __float2bfloat16(ox);
        o[bn*3+1] = __float2bfloat16(oy);
        o[bn*3+2] = __float2bfloat16(oz);
      } else {
        float* o = (float*)out;
        o[bn*3+0] = ox;
        o[bn*3+1] = oy;
        o[bn*3+2] = oz;
      }
    }
  }
}

// ---------------------------------------------------------------------------
extern "C" void kernel_launch(void* const* d_in, const int* in_sizes, int n_in,
                              void* d_out, int out_size, void* d_ws, size_t ws_size,
                              hipStream_t stream)
{
  (void)in_sizes; (void)n_in; (void)out_size; (void)ws_size;
  const int* nfeat = (const int*)d_in[1];

  float* ws   = (float*)d_ws;
  int*   flag = (int*)ws;                       // 16 floats reserved
  float* cvt  = ws + 16;                        // CVT_TOTAL floats
  float* posA = cvt + CVT_TOTAL;                // 1536
  float* posB = posA + NB*NN*3;                 // 1536
  float* zA   = posB + NB*NN*3;                 // 65536
  float* zB   = zA + NB*NN*NF;                  // 65536
  float* vecA = zB + NB*NN*NF;                  // 196608
  float* vecB = vecA + NB*NN*3*NF;              // 196608
  float* env  = vecB + NB*NN*3*NF;              // 65536

  prep_convert_kernel<<<512, 256, 0, stream>>>(
      d_in[0], nfeat, d_in[2], d_in[3], d_in[4], d_in[5], d_in[6], d_in[7],
      d_in[8], d_in[9], d_in[10], d_in[11], d_in[12], d_in[13], d_in[14],
      d_in[15], d_in[16], flag, cvt, posA, zA, vecA, env);

  layer_kernel<<<NB*64, 256, 0, stream>>>(
      posA, zA, vecA, env, cvt, 0, 0, posB, zB, vecB, flag, d_out);
  layer_kernel<<<NB*64, 256, 0, stream>>>(
      posB, zB, vecB, env, cvt, 1, 1, posA, zA, vecA, flag, d_out);
}